// Round 8
// baseline (666.538 us; speedup 1.0000x reference)
//
#include <hip/hip_runtime.h>
#include <cstdint>

// ---------------------------------------------------------------------------
// PerceiverResampler on MI355X (gfx950) — round 8:
//  * fold_kv/fold_q re-parallelized (6144/3072 blocks, one tile each);
//    bias via deterministic per-rowtile partials + tiny reduce kernel.
//  * latent merged GEMM + out-proj upgraded 64^2 -> 128^2 2-phase dbuf
//    with vectorized LDS epilogues.
//  * media GEMM + attention unchanged (round-7 verified).
// B=32 SEQ=512 DIM=1024 DEPTH=6 HEADS=8 DHEAD=64 INNER=512 NLAT=64
// ---------------------------------------------------------------------------

#define DEVINL __device__ __forceinline__

typedef __attribute__((ext_vector_type(8))) short short8_t;   // 8 x bf16
typedef __attribute__((ext_vector_type(4))) float f32x4;

DEVINL ushort f2bf(float f) {
  union { float f; uint32_t u; } c; c.f = f;
  uint32_t u = c.u;
  u += ((u >> 16) & 1u) + 0x7fffu;
  return (ushort)(u >> 16);
}
DEVINL float bf2f(ushort u) {
  union { uint32_t u; float f; } c; c.u = ((uint32_t)u) << 16;
  return c.f;
}
DEVINL f32x4 mfma16(short8_t a, short8_t b, f32x4 c) {
  return __builtin_amdgcn_mfma_f32_16x16x32_bf16(a, b, c, 0, 0, 0);
}
DEVINL void gld16(ushort* lds, const ushort* g) {
  __builtin_amdgcn_global_load_lds(
      (const __attribute__((address_space(1))) void*)g,
      (__attribute__((address_space(3))) void*)lds, 16, 0, 0);
}

// ---------------------------------------------------------------------------
// Media KV GEMM (round-7 verified): 256x256, 8 waves, BK=64, counted vmcnt(4),
// XOR-swizzled LDS, transposed-Cl single-pass epilogue.
__global__ __launch_bounds__(512, 2) void k_gemm256m(const ushort* __restrict__ A,
    const ushort* __restrict__ Bt, const float* __restrict__ bias,
    ushort* __restrict__ Kb, ushort* __restrict__ Vt) {
  extern __shared__ char lds[];
  constexpr int K = 1024, NT = 16;
  int tid = threadIdx.x, lane = tid & 63, w = tid >> 6;
  int wm = w >> 2, wn = w & 3;
  int fr = lane & 15;
  int fkb = (lane >> 4) << 4;
  int xorv = (fr & 7) << 4;
  int bid = blockIdx.x;
  int xcd = bid & 7, ii = bid >> 3;
  int m0 = (xcd * 8 + (ii >> 2)) * 256;
  int n0 = (ii & 3) * 256;
  int srow = w * 8 + (lane >> 3);
  int sce = ((lane & 7) ^ (lane >> 3)) << 3;
  const ushort* Ag = A + (size_t)(m0 + srow) * K + sce;
  const ushort* Bg = Bt + (size_t)(n0 + srow) * K + sce;
  f32x4 acc[8][4] = {};

  auto stA = [&](int t, int h) {
    ushort* d = (ushort*)(lds + (t % 3) * 32768 + h * 16384 + w * 1024);
    const ushort* s = Ag + (size_t)(h * 128) * K + t * 64;
    gld16(d, s);
    gld16((ushort*)((char*)d + 8192), s + (size_t)64 * K);
  };
  auto stB = [&](int t, int h) {
    ushort* d = (ushort*)(lds + 98304 + (t & 1) * 32768 + h * 16384 + w * 1024);
    const ushort* s = Bg + (size_t)(h * 128) * K + t * 64;
    gld16(d, s);
    gld16((ushort*)((char*)d + 8192), s + (size_t)64 * K);
  };
  stA(0, 0); stA(0, 1); stB(0, 0); stB(0, 1); stA(1, 0); stA(1, 1);

#define RD_AFR(DST, MQ)                                                        \
  _Pragma("unroll") for (int m2 = 0; m2 < 2; ++m2)                             \
    _Pragma("unroll") for (int kh = 0; kh < 2; ++kh)                           \
      DST[m2][kh] = *(const short8_t*)(ab +                                    \
          ((wm * 128 + (MQ + m2) * 16 + fr) << 7) + ((kh * 64 + fkb) ^ xorv));

#define CLUSTER(MQ, AFR)                                                       \
  __builtin_amdgcn_s_setprio(1);                                               \
  _Pragma("unroll") for (int kh = 0; kh < 2; ++kh)                             \
    _Pragma("unroll") for (int m2 = 0; m2 < 2; ++m2)                           \
      _Pragma("unroll") for (int nt = 0; nt < 4; ++nt)                         \
        acc[MQ + m2][nt] = mfma16(AFR[m2][kh], bfr[nt][kh], acc[MQ + m2][nt]); \
  __builtin_amdgcn_s_setprio(0);                                               \
  __builtin_amdgcn_s_barrier();

  for (int t = 0; t < NT; ++t) {
    const char* ab = lds + (t % 3) * 32768;
    const char* bb = lds + 98304 + (t & 1) * 32768;
    short8_t bfr[4][2], afrX[2][2], afrY[2][2];
    if (t + 1 < NT) asm volatile("s_waitcnt vmcnt(4)" ::: "memory");
    else            asm volatile("s_waitcnt vmcnt(0)" ::: "memory");
    __builtin_amdgcn_s_barrier();
#pragma unroll
    for (int nt = 0; nt < 4; ++nt)
#pragma unroll
      for (int kh = 0; kh < 2; ++kh)
        bfr[nt][kh] = *(const short8_t*)(bb +
            ((wn * 64 + nt * 16 + fr) << 7) + ((kh * 64 + fkb) ^ xorv));
    RD_AFR(afrX, 0);
    if (t + 1 < NT) stB(t + 1, 0);
    RD_AFR(afrY, 2);
    CLUSTER(0, afrX);
    if (t + 1 < NT) stB(t + 1, 1);
    RD_AFR(afrX, 4);
    CLUSTER(2, afrY);
    if (t + 2 < NT) stA(t + 2, 0);
    RD_AFR(afrY, 6);
    CLUSTER(4, afrX);
    if (t + 2 < NT) stA(t + 2, 1);
    CLUSTER(6, afrY);
  }
#undef RD_AFR
#undef CLUSTER

  __syncthreads();
  ushort* Cl = (ushort*)lds;
  constexpr int CLS = 264;
  bool isV = (n0 >= 512);
#pragma unroll
  for (int mt = 0; mt < 8; ++mt)
#pragma unroll
    for (int nt = 0; nt < 4; ++nt)
#pragma unroll
      for (int r = 0; r < 4; ++r) {
        int rl = wm * 128 + mt * 16 + ((lane >> 4) << 2) + r;
        int cl = wn * 64 + nt * 16 + fr;
        ushort v = f2bf(acc[mt][nt][r] + bias[n0 + cl]);
        if (!isV) Cl[rl * CLS + cl] = v;
        else      Cl[cl * CLS + rl] = v;
      }
  __syncthreads();
  int b_ = m0 >> 9;
  int jb = 64 + (m0 & 511);
#pragma unroll
  for (int q2 = 0; q2 < 16; ++q2) {
    int task = tid + q2 * 512;
    int rr2 = task >> 5, c8 = task & 31;
    short8_t vv = *(const short8_t*)&Cl[rr2 * CLS + c8 * 8];
    if (!isV)
      *(short8_t*)&Kb[((size_t)(b_ * 576 + jb + rr2) << 9) + n0 + c8 * 8] = vv;
    else
      *(short8_t*)&Vt[(size_t)(b_ * 512 + (n0 - 512) + rr2) * 576 + jb + c8 * 8] = vv;
  }
}

// ---------------------------------------------------------------------------
// Fused attention (round-7 verified): one block per (b,h), 8 waves,
// K/V LDS-staged via gld16 + XOR swizzle, dbuf + counted vmcnt(3).
__global__ __launch_bounds__(512) void k_attn(const ushort* __restrict__ Q,
    const ushort* __restrict__ Kb, const ushort* __restrict__ Vt,
    const int* __restrict__ amask, ushort* __restrict__ AO) {
  extern __shared__ char alds[];
  ushort* sim = (ushort*)alds;                    // [64][584]
  char* stg = alds + 74752;                       // 2 x 24576
  int bh = blockIdx.x;
  int h = bh & 7, b = bh >> 3;
  int tid = threadIdx.x, lane = tid & 63, w = tid >> 6;
  int rg = w >> 1, ch = w & 1;
  int fr = lane & 15;
  int fkb = (lane >> 4) << 4;
  int csrc8 = ((lane & 7) ^ (lane >> 3)) << 3;
  short8_t aq0, aq1;
  {
    int qi = rg * 16 + fr;
    const ushort* qp = Q + ((size_t)(b * 64 + qi) << 9) + h * 64 + ((lane >> 4) << 3);
    aq0 = *(const short8_t*)qp;
    aq1 = *(const short8_t*)(qp + 32);
  }
  unsigned mbits = 0;
#pragma unroll
  for (int c = 1; c < 9; ++c)
    if (amask[b * 512 + (c - 1) * 64 + lane]) mbits |= (1u << c);

  auto stageK = [&](int it, int buf) {
#pragma unroll
    for (int g = 0; g < 3; ++g) {
      int sr = w * 24 + g * 8 + (lane >> 3);
      ushort* d = (ushort*)(stg + buf * 24576 + (w * 24 + g * 8) * 128);
      gld16(d, Kb + ((size_t)(b * 576 + it * 192 + sr) << 9) + h * 64 + csrc8);
    }
  };
  auto stageV = [&](int it, int buf) {
#pragma unroll
    for (int g = 0; g < 3; ++g) {
      int sr = w * 8 + (lane >> 3);
      ushort* d = (ushort*)(stg + buf * 24576 + g * 8192 + w * 8 * 128);
      gld16(d, Vt + (size_t)(b * 512 + h * 64 + sr) * 576 + it * 192 + g * 64 + csrc8);
    }
  };

  stageK(0, 0);
  for (int it = 0; it < 3; ++it) {
    int buf = it & 1;
    __builtin_amdgcn_s_barrier();
    if (it + 1 < 3) {
      stageK(it + 1, buf ^ 1);
      asm volatile("s_waitcnt vmcnt(3)" ::: "memory");
    } else {
      asm volatile("s_waitcnt vmcnt(0)" ::: "memory");
    }
    __builtin_amdgcn_s_barrier();
    const char* kb_ = stg + buf * 24576;
#pragma unroll
    for (int ct = 0; ct < 6; ++ct) {
      int row_l = ch * 96 + ct * 16 + fr;
      const char* base = kb_ + row_l * 128;
      int sw = (row_l & 7) << 4;
      short8_t k0 = *(const short8_t*)(base + (fkb ^ sw));
      short8_t k1 = *(const short8_t*)(base + ((64 + fkb) ^ sw));
      f32x4 s4 = {};
      s4 = mfma16(aq0, k0, s4);
      s4 = mfma16(aq1, k1, s4);
#pragma unroll
      for (int r = 0; r < 4; ++r)
        sim[(rg * 16 + ((lane >> 4) << 2) + r) * 584 +
            it * 192 + ch * 96 + ct * 16 + fr] = f2bf(s4[r]);
    }
  }
  __syncthreads();
  for (int rr = 0; rr < 8; ++rr) {
    int row = w * 8 + rr;
    float vals[9];
    float m = -3.0e38f;
#pragma unroll
    for (int c = 0; c < 9; ++c) {
      float v = bf2f(sim[row * 584 + c * 64 + lane]);
      vals[c] = v;
      if (!((mbits >> c) & 1)) m = fmaxf(m, v);
    }
#pragma unroll
    for (int off = 32; off; off >>= 1) m = fmaxf(m, __shfl_xor(m, off));
    float ssum = 0.f;
    float p[9];
#pragma unroll
    for (int c = 0; c < 9; ++c) {
      p[c] = ((mbits >> c) & 1) ? 0.f : __expf(vals[c] - m);
      ssum += p[c];
    }
#pragma unroll
    for (int off = 32; off; off >>= 1) ssum += __shfl_xor(ssum, off);
    float inv = 1.0f / ssum;
#pragma unroll
    for (int c = 0; c < 9; ++c)
      sim[row * 584 + c * 64 + lane] = f2bf(p[c] * inv);
  }
  __syncthreads();
  f32x4 oacc[2] = {};
  stageV(0, 0);
  for (int it = 0; it < 3; ++it) {
    int buf = it & 1;
    __builtin_amdgcn_s_barrier();
    if (it + 1 < 3) {
      stageV(it + 1, buf ^ 1);
      asm volatile("s_waitcnt vmcnt(3)" ::: "memory");
    } else {
      asm volatile("s_waitcnt vmcnt(0)" ::: "memory");
    }
    __builtin_amdgcn_s_barrier();
#pragma unroll
    for (int g = 0; g < 3; ++g) {
      const char* vb_ = stg + buf * 24576 + g * 8192;
      const ushort* srow_ = &sim[(rg * 16 + fr) * 584 + it * 192 + g * 64];
      short8_t pa0 = *(const short8_t*)(srow_ + ((lane >> 4) << 3));
      short8_t pa1 = *(const short8_t*)(srow_ + 32 + ((lane >> 4) << 3));
#pragma unroll
      for (int dt = 0; dt < 2; ++dt) {
        int row_l = ch * 32 + dt * 16 + fr;
        const char* base = vb_ + row_l * 128;
        int sw = (row_l & 7) << 4;
        short8_t v0 = *(const short8_t*)(base + (fkb ^ sw));
        short8_t v1 = *(const short8_t*)(base + ((64 + fkb) ^ sw));
        oacc[dt] = mfma16(pa0, v0, oacc[dt]);
        oacc[dt] = mfma16(pa1, v1, oacc[dt]);
      }
    }
  }
#pragma unroll
  for (int dt = 0; dt < 2; ++dt)
#pragma unroll
    for (int r = 0; r < 4; ++r) {
      int i = rg * 16 + ((lane >> 4) << 2) + r;
      int d = ch * 32 + dt * 16 + fr;
      AO[((size_t)(b * 64 + i) << 9) + h * 64 + d] = f2bf(oacc[dt][r]);
    }
}

// ---------------------------------------------------------------------------
// Parallel fold kernels (one 32x32 tile per block) + deterministic bias
// partials pb[l][rt][2560]: [0,1024)=media, [1024,1536)=q, [1536,2560)=latkv.
__global__ __launch_bounds__(256) void k_fold_kv(const float* __restrict__ Wkv,
    const float* __restrict__ lnmg, const float* __restrict__ lnlg,
    const float* __restrict__ lnmb, const float* __restrict__ lnlb,
    ushort* __restrict__ wkvmT, ushort* __restrict__ wlatT,
    float* __restrict__ pb) {
  __shared__ float tile[32][33];
  __shared__ float pm[8][32], pl[8][32];
  int l = blockIdx.z, rt = blockIdx.y;
  int c0 = blockIdx.x * 32, r0 = rt * 32;
  const float* Wl = Wkv + (size_t)l * 1048576;
  int tx = threadIdx.x & 31, ty = threadIdx.x >> 5;
#pragma unroll
  for (int i = 0; i < 4; ++i)
    tile[ty + i * 8][tx] = Wl[(size_t)(r0 + ty + i * 8) * 1024 + c0 + tx];
  __syncthreads();
  float am = 0.f, al = 0.f;
#pragma unroll
  for (int i = 0; i < 4; ++i) {
    int r = ty * 4 + i;
    float wv = tile[r][tx];
    am += lnmb[l * 1024 + r0 + r] * wv;
    al += lnlb[l * 1024 + r0 + r] * wv;
  }
  pm[ty][tx] = am; pl[ty][tx] = al;
#pragma unroll
  for (int i = 0; i < 4; ++i) {
    int c = ty + i * 8;
    float wv = tile[tx][c];
    int r = r0 + tx;
    wkvmT[(size_t)l * 1048576 + (size_t)(c0 + c) * 1024 + r] =
        f2bf(wv * lnmg[l * 1024 + r]);
    wlatT[(size_t)l * 1572864 + (size_t)(512 + c0 + c) * 1024 + r] =
        f2bf(wv * lnlg[l * 1024 + r]);
  }
  __syncthreads();
  if (ty == 0) {
    float sm = 0.f, sl = 0.f;
#pragma unroll
    for (int k = 0; k < 8; ++k) { sm += pm[k][tx]; sl += pl[k][tx]; }
    pb[(size_t)(l * 32 + rt) * 2560 + c0 + tx] = sm;
    pb[(size_t)(l * 32 + rt) * 2560 + 1536 + c0 + tx] = sl;
  }
}

__global__ __launch_bounds__(256) void k_fold_q(const float* __restrict__ Wq,
    const float* __restrict__ lnlg, const float* __restrict__ lnlb,
    ushort* __restrict__ wlatT, float* __restrict__ pb) {
  __shared__ float tile[32][33];
  __shared__ float pq[8][32];
  int l = blockIdx.z, rt = blockIdx.y;
  int c0 = blockIdx.x * 32, r0 = rt * 32;
  const float* Wl = Wq + (size_t)l * 524288;
  int tx = threadIdx.x & 31, ty = threadIdx.x >> 5;
#pragma unroll
  for (int i = 0; i < 4; ++i)
    tile[ty + i * 8][tx] = Wl[(size_t)(r0 + ty + i * 8) * 512 + c0 + tx];
  __syncthreads();
  float aq = 0.f;
#pragma unroll
  for (int i = 0; i < 4; ++i) {
    int r = ty * 4 + i;
    aq += lnlb[l * 1024 + r0 + r] * tile[r][tx];
  }
  pq[ty][tx] = aq;
#pragma unroll
  for (int i = 0; i < 4; ++i) {
    int c = ty + i * 8;
    float wv = tile[tx][c];
    int r = r0 + tx;
    wlatT[(size_t)l * 1572864 + (size_t)(c0 + c) * 1024 + r] =
        f2bf(wv * lnlg[l * 1024 + r] * 0.125f);
  }
  __syncthreads();
  if (ty == 0) {
    float s = 0.f;
#pragma unroll
    for (int k = 0; k < 8; ++k) s += pq[k][tx];
    pb[(size_t)(l * 32 + rt) * 2560 + 1024 + c0 + tx] = s;
  }
}

// reduce partials -> bkvm[6][1024], blat[6][1536]. grid (10, 6), block 256.
__global__ __launch_bounds__(256) void k_bias_red(const float* __restrict__ pb,
    float* __restrict__ bkvm, float* __restrict__ blat) {
  int l = blockIdx.y;
  int c = blockIdx.x * 256 + threadIdx.x;     // 0..2559
  float s = 0.f;
  for (int rt = 0; rt < 32; ++rt)
    s += pb[(size_t)(l * 32 + rt) * 2560 + c];
  if (c < 1024)       bkvm[l * 1024 + c] = s;
  else if (c < 1536)  blat[l * 1536 + (c - 1024)] = s * 0.125f;
  else                blat[l * 1536 + 512 + (c - 1536)] = s;
}

__global__ __launch_bounds__(256) void k_fold_out(const float* __restrict__ Wout,
    ushort* __restrict__ woutT) {
  __shared__ float tile[32][33];
  int l = blockIdx.z;
  const float* Wl = Wout + (size_t)l * 524288;
  int r0 = blockIdx.y * 32, c0 = blockIdx.x * 32;
  int tx = threadIdx.x & 31, ty = threadIdx.x >> 5;
#pragma unroll
  for (int i = 0; i < 4; ++i)
    tile[ty + i * 8][tx] = Wl[(size_t)(r0 + ty + i * 8) * 1024 + c0 + tx];
  __syncthreads();
#pragma unroll
  for (int i = 0; i < 4; ++i) {
    int jl = ty + i * 8;
    woutT[(size_t)l * 524288 + (size_t)(c0 + jl) * 512 + r0 + tx] = f2bf(tile[tx][jl]);
  }
}

// ---------------------------------------------------------------------------
__global__ __launch_bounds__(256) void k_rownorm(const float* __restrict__ in,
    const float* __restrict__ pos, ushort* __restrict__ out) {
  int row = blockIdx.x, t = threadIdx.x;
  float4 v = *(const float4*)(in + (size_t)row * 1024 + t * 4);
  if (pos) {
    float4 p = *(const float4*)(pos + (size_t)(row & 511) * 1024 + t * 4);
    v.x += p.x; v.y += p.y; v.z += p.z; v.w += p.w;
  }
  float s = v.x + v.y + v.z + v.w;
  float q = v.x * v.x + v.y * v.y + v.z * v.z + v.w * v.w;
#pragma unroll
  for (int off = 32; off; off >>= 1) { s += __shfl_xor(s, off); q += __shfl_xor(q, off); }
  __shared__ float rs[4], rq[4];
  if ((t & 63) == 0) { rs[t >> 6] = s; rq[t >> 6] = q; }
  __syncthreads();
  s = rs[0] + rs[1] + rs[2] + rs[3];
  q = rq[0] + rq[1] + rq[2] + rq[3];
  float mean = s * (1.0f / 1024.0f);
  float var = q * (1.0f / 1024.0f) - mean * mean;
  float rstd = rsqrtf(var + 1e-5f);
  ushort4 o;
  o.x = f2bf((v.x - mean) * rstd);
  o.y = f2bf((v.y - mean) * rstd);
  o.z = f2bf((v.z - mean) * rstd);
  o.w = f2bf((v.w - mean) * rstd);
  *(ushort4*)(out + (size_t)row * 1024 + t * 4) = o;
}

__global__ __launch_bounds__(256) void k_finalln(const float* __restrict__ in,
    const float* __restrict__ g, const float* __restrict__ b, float* __restrict__ out) {
  int row = blockIdx.x, t = threadIdx.x;
  float4 v = *(const float4*)(in + (size_t)row * 1024 + t * 4);
  float s = v.x + v.y + v.z + v.w;
  float q = v.x * v.x + v.y * v.y + v.z * v.z + v.w * v.w;
#pragma unroll
  for (int off = 32; off; off >>= 1) { s += __shfl_xor(s, off); q += __shfl_xor(q, off); }
  __shared__ float rs[4], rq[4];
  if ((t & 63) == 0) { rs[t >> 6] = s; rq[t >> 6] = q; }
  __syncthreads();
  s = rs[0] + rs[1] + rs[2] + rs[3];
  q = rq[0] + rq[1] + rq[2] + rq[3];
  float mean = s * (1.0f / 1024.0f);
  float var = q * (1.0f / 1024.0f) - mean * mean;
  float rstd = rsqrtf(var + 1e-5f);
  float4 g4 = *(const float4*)(g + t * 4);
  float4 b4 = *(const float4*)(b + t * 4);
  float4 o;
  o.x = (v.x - mean) * rstd * g4.x + b4.x;
  o.y = (v.y - mean) * rstd * g4.y + b4.y;
  o.z = (v.z - mean) * rstd * g4.z + b4.z;
  o.w = (v.w - mean) * rstd * g4.w + b4.w;
  *(float4*)(out + (size_t)row * 1024 + t * 4) = o;
}

__global__ __launch_bounds__(256) void k_latinit(const float* __restrict__ latents,
                                                 float* __restrict__ lat) {
  int row = blockIdx.x, t = threadIdx.x;
  *(float4*)(lat + (size_t)row * 1024 + t * 4) =
      *(const float4*)(latents + (size_t)(row & 63) * 1024 + t * 4);
}

// ---------------------------------------------------------------------------
// 128^2 2-phase dbuf GEMM. 4 waves of 64x64 (4x4 frags).
// MODE 3: latent merged: n0<512 -> q; <1024 -> K_lat; else V_lat->Vt.
// MODE 2: f32 residual += (out-proj), direct stores.
template <int MODE>
__global__ __launch_bounds__(256) void k_g128(const ushort* __restrict__ A,
    const ushort* __restrict__ Bt, const float* __restrict__ bias,
    ushort* __restrict__ o0, ushort* __restrict__ o1, ushort* __restrict__ o2,
    float* __restrict__ of, int N, int K) {
  __shared__ char pool[34816];            // stage dbuf 32KB | Cl[128][136]
  int tid = threadIdx.x, lane = tid & 63, w = tid >> 6;
  int wr = w >> 1, wc = w & 1;
  int m0 = blockIdx.y * 128, n0 = blockIdx.x * 128;
  f32x4 acc[4][4] = {};
  const ushort* Ag = A + (size_t)(m0 + w * 32 + (lane >> 2)) * K + (lane & 3) * 8;
  const ushort* Bg = Bt + (size_t)(n0 + w * 32 + (lane >> 2)) * K + (lane & 3) * 8;
  int fr = lane & 15, fk = (lane >> 4) << 3;
  int ntk = K >> 5;
  auto stA = [&](int k0, int cur) {
    ushort* d = (ushort*)pool + cur * 4096 + w * 1024;
    gld16(d, Ag + k0);
    gld16(d + 512, Ag + k0 + (size_t)16 * K);
  };
  auto stB = [&](int k0, int cur) {
    ushort* d = (ushort*)(pool + 16384) + cur * 4096 + w * 1024;
    gld16(d, Bg + k0);
    gld16(d + 512, Bg + k0 + (size_t)16 * K);
  };
  stA(0, 0); stB(0, 0);
  __syncthreads();
  for (int t = 0; t < ntk; ++t) {
    int cur = t & 1;
    if (t + 1 < ntk) { stA((t + 1) << 5, cur ^ 1); stB((t + 1) << 5, cur ^ 1); }
    const ushort* ab = (ushort*)pool + cur * 4096;
    const ushort* bb = (ushort*)(pool + 16384) + cur * 4096;
    short8_t a[4], b[4];
#pragma unroll
    for (int mt = 0; mt < 4; ++mt)
      a[mt] = *(const short8_t*)(ab + (wr * 64 + mt * 16 + fr) * 32 + fk);
#pragma unroll
    for (int nt = 0; nt < 4; ++nt)
      b[nt] = *(const short8_t*)(bb + (wc * 64 + nt * 16 + fr) * 32 + fk);
#pragma unroll
    for (int mt = 0; mt < 4; ++mt)
#pragma unroll
      for (int nt = 0; nt < 4; ++nt)
        acc[mt][nt] = mfma16(a[mt], b[nt], acc[mt][nt]);
    __syncthreads();
  }
  if constexpr (MODE == 2) {
#pragma unroll
    for (int mt = 0; mt < 4; ++mt)
#pragma unroll
      for (int nt = 0; nt < 4; ++nt)
#pragma unroll
        for (int r = 0; r < 4; ++r) {
          int row = m0 + wr * 64 + mt * 16 + ((lane >> 4) << 2) + r;
          int col = n0 + wc * 64 + nt * 16 + fr;
          of[(size_t)row * N + col] += acc[mt][nt][r];
        }
  } else {
    // MODE 3: LDS-staged vectorized epilogue
    ushort* Cl = (ushort*)pool;
    constexpr int CLS = 136;
    bool isV = (n0 >= 1024);
#pragma unroll
    for (int mt = 0; mt < 4; ++mt)
#pragma unroll
      for (int nt = 0; nt < 4; ++nt)
#pragma unroll
        for (int r = 0; r < 4; ++r) {
          int rl = wr * 64 + mt * 16 + ((lane >> 4) << 2) + r;
          int cl = wc * 64 + nt * 16 + fr;
          ushort v = f2bf(acc[mt][nt][r] + bias[n0 + cl]);
          if (!isV) Cl[rl * CLS + cl] = v;
          else      Cl[cl * CLS + rl] = v;
        }
    __syncthreads();
#pragma unroll
    for (int q = 0; q < 8; ++q) {
      int task = tid + q * 256;            // 2048: 128 rows x 16 chunks
      int rr = task >> 4, ck = task & 15;
      short8_t vv = *(const short8_t*)&Cl[rr * CLS + ck * 8];
      if (n0 < 512) {
        *(short8_t*)&o0[(size_t)(m0 + rr) * 512 + n0 + ck * 8] = vv;
      } else if (n0 < 1024) {
        int row = m0 + rr, b_ = row >> 6, i = row & 63;
        *(short8_t*)&o1[((size_t)(b_ * 576 + i) << 9) + (n0 - 512) + ck * 8] = vv;
      } else {
        // Cl[d][i]: rr = d-local, ck covers i 0..127 over 2 batches
        int dg = n0 - 1024 + rr;
        int b_ = (m0 >> 6) + (ck >> 3);
        int i0 = (ck & 7) * 8;
        *(short8_t*)&o2[((size_t)(b_ * 512 + dg)) * 576 + i0] = vv;
      }
    }
  }
}

// ---------------------------------------------------------------------------
extern "C" void kernel_launch(void* const* d_in, const int* in_sizes, int n_in,
                              void* d_out, int out_size, void* d_ws, size_t ws_size,
                              hipStream_t stream) {
  const float* x       = (const float*)d_in[0];
  const int*   amask   = (const int*)d_in[1];
  const float* latents = (const float*)d_in[2];
  const float* pos     = (const float*)d_in[3];
  const float* lnmg    = (const float*)d_in[4];
  const float* lnmb    = (const float*)d_in[5];
  const float* lnlg    = (const float*)d_in[6];
  const float* lnlb    = (const float*)d_in[7];
  const float* Wq      = (const float*)d_in[8];
  const float* Wkv     = (const float*)d_in[9];
  const float* Wout    = (const float*)d_in[10];
  const float* fg      = (const float*)d_in[11];
  const float* fb      = (const float*)d_in[12];
  float* out = (float*)d_out;
  char* ws = (char*)d_ws;

  ushort* xhat  = (ushort*)(ws + 0);           // [16384][1024] bf16   32 MiB
  ushort* wkvmT = (ushort*)(ws + 33554432);    // [6][1024][1024]      12 MiB
  ushort* wlatT = (ushort*)(ws + 46137344);    // [6][1536][1024]      18 MiB
  ushort* woutT = (ushort*)(ws + 65011712);    // [6][1024][512]        6 MiB
  float*  bkvm  = (float*)(ws + 71303168);     // [6][1024]
  float*  blat  = (float*)(ws + 71327744);     // [6][1536]
  float*  lat   = (float*)(ws + 71364608);     // [2048][1024] f32      8 MiB
  ushort* lhat  = (ushort*)(ws + 79753216);    // [2048][1024] bf16     4 MiB
  ushort* qbuf  = (ushort*)(ws + 83947520);    // [2048][512]  bf16     2 MiB
  ushort* Kbuf  = (ushort*)(ws + 86044672);    // [32][576][512]       18 MiB
  ushort* Vt    = (ushort*)(ws + 104919040);   // [32][512][576]       18 MiB
  ushort* aobuf = (ushort*)(ws + 123793408);   // [2048][512]           2 MiB
  float*  pb    = (float*)(ws + 125890560);    // [6][32][2560] f32     2 MiB

  (void)hipFuncSetAttribute((const void*)k_gemm256m,
                            hipFuncAttributeMaxDynamicSharedMemorySize, 163840);
  (void)hipFuncSetAttribute((const void*)k_attn,
                            hipFuncAttributeMaxDynamicSharedMemorySize, 131072);

  dim3 B256(256);
  k_fold_kv<<<dim3(32, 32, 6), B256, 0, stream>>>(Wkv, lnmg, lnlg, lnmb, lnlb,
                                                  wkvmT, wlatT, pb);
  k_fold_q<<<dim3(16, 32, 6), B256, 0, stream>>>(Wq, lnlg, lnlb, wlatT, pb);
  k_fold_out<<<dim3(32, 16, 6), B256, 0, stream>>>(Wout, woutT);
  k_bias_red<<<dim3(10, 6), B256, 0, stream>>>(pb, bkvm, blat);
  k_rownorm<<<16384, B256, 0, stream>>>(x, pos, xhat);
  k_latinit<<<2048, B256, 0, stream>>>(latents, lat);

  for (int l = 0; l < 6; ++l) {
    k_rownorm<<<2048, B256, 0, stream>>>(lat, nullptr, lhat);
    // merged latent GEMM: [q | K_lat | V_lat], 128^2, 192 blocks
    k_g128<3><<<dim3(12, 16), B256, 0, stream>>>(
        lhat, wlatT + (size_t)l * 1572864, blat + l * 1536,
        qbuf, Kbuf, Vt, nullptr, 1536, 1024);
    // media KV: 256^2 pipelined
    k_gemm256m<<<dim3(256), dim3(512), 163840, stream>>>(
        xhat, wkvmT + (size_t)l * 1048576, bkvm + l * 1024, Kbuf, Vt);
    // attention: one block per (b,h)
    k_attn<<<dim3(256), dim3(512), 123904, stream>>>(qbuf, Kbuf, Vt, amask, aobuf);
    // lat += attn_out @ Wout, 128^2, 128 blocks
    k_g128<2><<<dim3(8, 16), B256, 0, stream>>>(
        aobuf, woutT + (size_t)l * 524288, nullptr,
        nullptr, nullptr, nullptr, lat, 1024, 512);
  }
  k_finalln<<<2048, B256, 0, stream>>>(lat, fg, fb, out);
}

// Round 9
// 595.459 us; speedup vs baseline: 1.1194x; 1.1194x over previous
//
#include <hip/hip_runtime.h>
#include <cstdint>

// ---------------------------------------------------------------------------
// PerceiverResampler on MI355X (gfx950) — round 9:
//  * REVERT latent/out-proj to round-7 64^2 2-phase kernels (768/512 blocks)
//    — round-8's 128^2 retile was grid-starved (192/128 blocks, −11 µs/layer).
//  * keep round-8 parallel folds + bias_red, round-8 media GEMM (41.5 µs,
//    conflicts 262K) and round-7 attention.
//  * attn micro-opt: stageV(0) issued before softmax (V0 latency hides
//    under softmax VALU; vmcnt(3) in PV loop still counts correctly).
// B=32 SEQ=512 DIM=1024 DEPTH=6 HEADS=8 DHEAD=64 INNER=512 NLAT=64
// ---------------------------------------------------------------------------

#define DEVINL __device__ __forceinline__

typedef __attribute__((ext_vector_type(8))) short short8_t;   // 8 x bf16
typedef __attribute__((ext_vector_type(4))) float f32x4;

DEVINL ushort f2bf(float f) {
  union { float f; uint32_t u; } c; c.f = f;
  uint32_t u = c.u;
  u += ((u >> 16) & 1u) + 0x7fffu;
  return (ushort)(u >> 16);
}
DEVINL float bf2f(ushort u) {
  union { uint32_t u; float f; } c; c.u = ((uint32_t)u) << 16;
  return c.f;
}
DEVINL f32x4 mfma16(short8_t a, short8_t b, f32x4 c) {
  return __builtin_amdgcn_mfma_f32_16x16x32_bf16(a, b, c, 0, 0, 0);
}
DEVINL void gld16(ushort* lds, const ushort* g) {
  __builtin_amdgcn_global_load_lds(
      (const __attribute__((address_space(1))) void*)g,
      (__attribute__((address_space(3))) void*)lds, 16, 0, 0);
}

// ---------------------------------------------------------------------------
// Media KV GEMM (verified r8): 256x256, 8 waves, BK=64, counted vmcnt(4),
// XOR-swizzled LDS, transposed-Cl single-pass epilogue.
__global__ __launch_bounds__(512, 2) void k_gemm256m(const ushort* __restrict__ A,
    const ushort* __restrict__ Bt, const float* __restrict__ bias,
    ushort* __restrict__ Kb, ushort* __restrict__ Vt) {
  extern __shared__ char lds[];
  constexpr int K = 1024, NT = 16;
  int tid = threadIdx.x, lane = tid & 63, w = tid >> 6;
  int wm = w >> 2, wn = w & 3;
  int fr = lane & 15;
  int fkb = (lane >> 4) << 4;
  int xorv = (fr & 7) << 4;
  int bid = blockIdx.x;
  int xcd = bid & 7, ii = bid >> 3;
  int m0 = (xcd * 8 + (ii >> 2)) * 256;
  int n0 = (ii & 3) * 256;
  int srow = w * 8 + (lane >> 3);
  int sce = ((lane & 7) ^ (lane >> 3)) << 3;
  const ushort* Ag = A + (size_t)(m0 + srow) * K + sce;
  const ushort* Bg = Bt + (size_t)(n0 + srow) * K + sce;
  f32x4 acc[8][4] = {};

  auto stA = [&](int t, int h) {
    ushort* d = (ushort*)(lds + (t % 3) * 32768 + h * 16384 + w * 1024);
    const ushort* s = Ag + (size_t)(h * 128) * K + t * 64;
    gld16(d, s);
    gld16((ushort*)((char*)d + 8192), s + (size_t)64 * K);
  };
  auto stB = [&](int t, int h) {
    ushort* d = (ushort*)(lds + 98304 + (t & 1) * 32768 + h * 16384 + w * 1024);
    const ushort* s = Bg + (size_t)(h * 128) * K + t * 64;
    gld16(d, s);
    gld16((ushort*)((char*)d + 8192), s + (size_t)64 * K);
  };
  stA(0, 0); stA(0, 1); stB(0, 0); stB(0, 1); stA(1, 0); stA(1, 1);

#define RD_AFR(DST, MQ)                                                        \
  _Pragma("unroll") for (int m2 = 0; m2 < 2; ++m2)                             \
    _Pragma("unroll") for (int kh = 0; kh < 2; ++kh)                           \
      DST[m2][kh] = *(const short8_t*)(ab +                                    \
          ((wm * 128 + (MQ + m2) * 16 + fr) << 7) + ((kh * 64 + fkb) ^ xorv));

#define CLUSTER(MQ, AFR)                                                       \
  __builtin_amdgcn_s_setprio(1);                                               \
  _Pragma("unroll") for (int kh = 0; kh < 2; ++kh)                             \
    _Pragma("unroll") for (int m2 = 0; m2 < 2; ++m2)                           \
      _Pragma("unroll") for (int nt = 0; nt < 4; ++nt)                         \
        acc[MQ + m2][nt] = mfma16(AFR[m2][kh], bfr[nt][kh], acc[MQ + m2][nt]); \
  __builtin_amdgcn_s_setprio(0);                                               \
  __builtin_amdgcn_s_barrier();

  for (int t = 0; t < NT; ++t) {
    const char* ab = lds + (t % 3) * 32768;
    const char* bb = lds + 98304 + (t & 1) * 32768;
    short8_t bfr[4][2], afrX[2][2], afrY[2][2];
    if (t + 1 < NT) asm volatile("s_waitcnt vmcnt(4)" ::: "memory");
    else            asm volatile("s_waitcnt vmcnt(0)" ::: "memory");
    __builtin_amdgcn_s_barrier();
#pragma unroll
    for (int nt = 0; nt < 4; ++nt)
#pragma unroll
      for (int kh = 0; kh < 2; ++kh)
        bfr[nt][kh] = *(const short8_t*)(bb +
            ((wn * 64 + nt * 16 + fr) << 7) + ((kh * 64 + fkb) ^ xorv));
    RD_AFR(afrX, 0);
    if (t + 1 < NT) stB(t + 1, 0);
    RD_AFR(afrY, 2);
    CLUSTER(0, afrX);
    if (t + 1 < NT) stB(t + 1, 1);
    RD_AFR(afrX, 4);
    CLUSTER(2, afrY);
    if (t + 2 < NT) stA(t + 2, 0);
    RD_AFR(afrY, 6);
    CLUSTER(4, afrX);
    if (t + 2 < NT) stA(t + 2, 1);
    CLUSTER(6, afrY);
  }
#undef RD_AFR
#undef CLUSTER

  __syncthreads();
  ushort* Cl = (ushort*)lds;
  constexpr int CLS = 264;
  bool isV = (n0 >= 512);
#pragma unroll
  for (int mt = 0; mt < 8; ++mt)
#pragma unroll
    for (int nt = 0; nt < 4; ++nt)
#pragma unroll
      for (int r = 0; r < 4; ++r) {
        int rl = wm * 128 + mt * 16 + ((lane >> 4) << 2) + r;
        int cl = wn * 64 + nt * 16 + fr;
        ushort v = f2bf(acc[mt][nt][r] + bias[n0 + cl]);
        if (!isV) Cl[rl * CLS + cl] = v;
        else      Cl[cl * CLS + rl] = v;
      }
  __syncthreads();
  int b_ = m0 >> 9;
  int jb = 64 + (m0 & 511);
#pragma unroll
  for (int q2 = 0; q2 < 16; ++q2) {
    int task = tid + q2 * 512;
    int rr2 = task >> 5, c8 = task & 31;
    short8_t vv = *(const short8_t*)&Cl[rr2 * CLS + c8 * 8];
    if (!isV)
      *(short8_t*)&Kb[((size_t)(b_ * 576 + jb + rr2) << 9) + n0 + c8 * 8] = vv;
    else
      *(short8_t*)&Vt[(size_t)(b_ * 512 + (n0 - 512) + rr2) * 576 + jb + c8 * 8] = vv;
  }
}

// ---------------------------------------------------------------------------
// Fused attention: one block per (b,h), 8 waves, K/V LDS-staged via gld16 +
// XOR swizzle, dbuf + counted vmcnt(3). stageV(0) hoisted before softmax.
__global__ __launch_bounds__(512) void k_attn(const ushort* __restrict__ Q,
    const ushort* __restrict__ Kb, const ushort* __restrict__ Vt,
    const int* __restrict__ amask, ushort* __restrict__ AO) {
  extern __shared__ char alds[];
  ushort* sim = (ushort*)alds;                    // [64][584]
  char* stg = alds + 74752;                       // 2 x 24576
  int bh = blockIdx.x;
  int h = bh & 7, b = bh >> 3;
  int tid = threadIdx.x, lane = tid & 63, w = tid >> 6;
  int rg = w >> 1, ch = w & 1;
  int fr = lane & 15;
  int fkb = (lane >> 4) << 4;
  int csrc8 = ((lane & 7) ^ (lane >> 3)) << 3;
  short8_t aq0, aq1;
  {
    int qi = rg * 16 + fr;
    const ushort* qp = Q + ((size_t)(b * 64 + qi) << 9) + h * 64 + ((lane >> 4) << 3);
    aq0 = *(const short8_t*)qp;
    aq1 = *(const short8_t*)(qp + 32);
  }
  unsigned mbits = 0;
#pragma unroll
  for (int c = 1; c < 9; ++c)
    if (amask[b * 512 + (c - 1) * 64 + lane]) mbits |= (1u << c);

  auto stageK = [&](int it, int buf) {
#pragma unroll
    for (int g = 0; g < 3; ++g) {
      int sr = w * 24 + g * 8 + (lane >> 3);
      ushort* d = (ushort*)(stg + buf * 24576 + (w * 24 + g * 8) * 128);
      gld16(d, Kb + ((size_t)(b * 576 + it * 192 + sr) << 9) + h * 64 + csrc8);
    }
  };
  auto stageV = [&](int it, int buf) {
#pragma unroll
    for (int g = 0; g < 3; ++g) {
      int sr = w * 8 + (lane >> 3);
      ushort* d = (ushort*)(stg + buf * 24576 + g * 8192 + w * 8 * 128);
      gld16(d, Vt + (size_t)(b * 512 + h * 64 + sr) * 576 + it * 192 + g * 64 + csrc8);
    }
  };

  // ---- phase 1: S = Q@K^T
  stageK(0, 0);
  for (int it = 0; it < 3; ++it) {
    int buf = it & 1;
    __builtin_amdgcn_s_barrier();
    if (it + 1 < 3) {
      stageK(it + 1, buf ^ 1);
      asm volatile("s_waitcnt vmcnt(3)" ::: "memory");
    } else {
      asm volatile("s_waitcnt vmcnt(0)" ::: "memory");
    }
    __builtin_amdgcn_s_barrier();
    const char* kb_ = stg + buf * 24576;
#pragma unroll
    for (int ct = 0; ct < 6; ++ct) {
      int row_l = ch * 96 + ct * 16 + fr;
      const char* base = kb_ + row_l * 128;
      int sw = (row_l & 7) << 4;
      short8_t k0 = *(const short8_t*)(base + (fkb ^ sw));
      short8_t k1 = *(const short8_t*)(base + ((64 + fkb) ^ sw));
      f32x4 s4 = {};
      s4 = mfma16(aq0, k0, s4);
      s4 = mfma16(aq1, k1, s4);
#pragma unroll
      for (int r = 0; r < 4; ++r)
        sim[(rg * 16 + ((lane >> 4) << 2) + r) * 584 +
            it * 192 + ch * 96 + ct * 16 + fr] = f2bf(s4[r]);
    }
  }
  __syncthreads();          // all QK^T reads of buf0 complete; sim visible
  stageV(0, 0);             // issue early: V0 latency hides under softmax
  // ---- phase 2: masked softmax, 8 rows per wave
  for (int rr = 0; rr < 8; ++rr) {
    int row = w * 8 + rr;
    float vals[9];
    float m = -3.0e38f;
#pragma unroll
    for (int c = 0; c < 9; ++c) {
      float v = bf2f(sim[row * 584 + c * 64 + lane]);
      vals[c] = v;
      if (!((mbits >> c) & 1)) m = fmaxf(m, v);
    }
#pragma unroll
    for (int off = 32; off; off >>= 1) m = fmaxf(m, __shfl_xor(m, off));
    float ssum = 0.f;
    float p[9];
#pragma unroll
    for (int c = 0; c < 9; ++c) {
      p[c] = ((mbits >> c) & 1) ? 0.f : __expf(vals[c] - m);
      ssum += p[c];
    }
#pragma unroll
    for (int off = 32; off; off >>= 1) ssum += __shfl_xor(ssum, off);
    float inv = 1.0f / ssum;
#pragma unroll
    for (int c = 0; c < 9; ++c)
      sim[row * 584 + c * 64 + lane] = f2bf(p[c] * inv);
  }
  __syncthreads();
  // ---- phase 3: O = P@V
  f32x4 oacc[2] = {};
  for (int it = 0; it < 3; ++it) {
    int buf = it & 1;
    __builtin_amdgcn_s_barrier();
    if (it + 1 < 3) {
      stageV(it + 1, buf ^ 1);
      asm volatile("s_waitcnt vmcnt(3)" ::: "memory");
    } else {
      asm volatile("s_waitcnt vmcnt(0)" ::: "memory");
    }
    __builtin_amdgcn_s_barrier();
#pragma unroll
    for (int g = 0; g < 3; ++g) {
      const char* vb_ = stg + buf * 24576 + g * 8192;
      const ushort* srow_ = &sim[(rg * 16 + fr) * 584 + it * 192 + g * 64];
      short8_t pa0 = *(const short8_t*)(srow_ + ((lane >> 4) << 3));
      short8_t pa1 = *(const short8_t*)(srow_ + 32 + ((lane >> 4) << 3));
#pragma unroll
      for (int dt = 0; dt < 2; ++dt) {
        int row_l = ch * 32 + dt * 16 + fr;
        const char* base = vb_ + row_l * 128;
        int sw = (row_l & 7) << 4;
        short8_t v0 = *(const short8_t*)(base + (fkb ^ sw));
        short8_t v1 = *(const short8_t*)(base + ((64 + fkb) ^ sw));
        oacc[dt] = mfma16(pa0, v0, oacc[dt]);
        oacc[dt] = mfma16(pa1, v1, oacc[dt]);
      }
    }
  }
#pragma unroll
  for (int dt = 0; dt < 2; ++dt)
#pragma unroll
    for (int r = 0; r < 4; ++r) {
      int i = rg * 16 + ((lane >> 4) << 2) + r;
      int d = ch * 32 + dt * 16 + fr;
      AO[((size_t)(b * 64 + i) << 9) + h * 64 + d] = f2bf(oacc[dt][r]);
    }
}

// ---------------------------------------------------------------------------
// Parallel fold kernels (one 32x32 tile per block) + deterministic bias
// partials pb[l][rt][2560]: [0,1024)=media, [1024,1536)=q, [1536,2560)=latkv.
__global__ __launch_bounds__(256) void k_fold_kv(const float* __restrict__ Wkv,
    const float* __restrict__ lnmg, const float* __restrict__ lnlg,
    const float* __restrict__ lnmb, const float* __restrict__ lnlb,
    ushort* __restrict__ wkvmT, ushort* __restrict__ wlatT,
    float* __restrict__ pb) {
  __shared__ float tile[32][33];
  __shared__ float pm[8][32], pl[8][32];
  int l = blockIdx.z, rt = blockIdx.y;
  int c0 = blockIdx.x * 32, r0 = rt * 32;
  const float* Wl = Wkv + (size_t)l * 1048576;
  int tx = threadIdx.x & 31, ty = threadIdx.x >> 5;
#pragma unroll
  for (int i = 0; i < 4; ++i)
    tile[ty + i * 8][tx] = Wl[(size_t)(r0 + ty + i * 8) * 1024 + c0 + tx];
  __syncthreads();
  float am = 0.f, al = 0.f;
#pragma unroll
  for (int i = 0; i < 4; ++i) {
    int r = ty * 4 + i;
    float wv = tile[r][tx];
    am += lnmb[l * 1024 + r0 + r] * wv;
    al += lnlb[l * 1024 + r0 + r] * wv;
  }
  pm[ty][tx] = am; pl[ty][tx] = al;
#pragma unroll
  for (int i = 0; i < 4; ++i) {
    int c = ty + i * 8;
    float wv = tile[tx][c];
    int r = r0 + tx;
    wkvmT[(size_t)l * 1048576 + (size_t)(c0 + c) * 1024 + r] =
        f2bf(wv * lnmg[l * 1024 + r]);
    wlatT[(size_t)l * 1572864 + (size_t)(512 + c0 + c) * 1024 + r] =
        f2bf(wv * lnlg[l * 1024 + r]);
  }
  __syncthreads();
  if (ty == 0) {
    float sm = 0.f, sl = 0.f;
#pragma unroll
    for (int k = 0; k < 8; ++k) { sm += pm[k][tx]; sl += pl[k][tx]; }
    pb[(size_t)(l * 32 + rt) * 2560 + c0 + tx] = sm;
    pb[(size_t)(l * 32 + rt) * 2560 + 1536 + c0 + tx] = sl;
  }
}

__global__ __launch_bounds__(256) void k_fold_q(const float* __restrict__ Wq,
    const float* __restrict__ lnlg, const float* __restrict__ lnlb,
    ushort* __restrict__ wlatT, float* __restrict__ pb) {
  __shared__ float tile[32][33];
  __shared__ float pq[8][32];
  int l = blockIdx.z, rt = blockIdx.y;
  int c0 = blockIdx.x * 32, r0 = rt * 32;
  const float* Wl = Wq + (size_t)l * 524288;
  int tx = threadIdx.x & 31, ty = threadIdx.x >> 5;
#pragma unroll
  for (int i = 0; i < 4; ++i)
    tile[ty + i * 8][tx] = Wl[(size_t)(r0 + ty + i * 8) * 512 + c0 + tx];
  __syncthreads();
  float aq = 0.f;
#pragma unroll
  for (int i = 0; i < 4; ++i) {
    int r = ty * 4 + i;
    aq += lnlb[l * 1024 + r0 + r] * tile[r][tx];
  }
  pq[ty][tx] = aq;
#pragma unroll
  for (int i = 0; i < 4; ++i) {
    int c = ty + i * 8;
    float wv = tile[tx][c];
    int r = r0 + tx;
    wlatT[(size_t)l * 1572864 + (size_t)(c0 + c) * 1024 + r] =
        f2bf(wv * lnlg[l * 1024 + r] * 0.125f);
  }
  __syncthreads();
  if (ty == 0) {
    float s = 0.f;
#pragma unroll
    for (int k = 0; k < 8; ++k) s += pq[k][tx];
    pb[(size_t)(l * 32 + rt) * 2560 + 1024 + c0 + tx] = s;
  }
}

// reduce partials -> bkvm[6][1024], blat[6][1536]. grid (10, 6), block 256.
__global__ __launch_bounds__(256) void k_bias_red(const float* __restrict__ pb,
    float* __restrict__ bkvm, float* __restrict__ blat) {
  int l = blockIdx.y;
  int c = blockIdx.x * 256 + threadIdx.x;     // 0..2559
  float s = 0.f;
  for (int rt = 0; rt < 32; ++rt)
    s += pb[(size_t)(l * 32 + rt) * 2560 + c];
  if (c < 1024)       bkvm[l * 1024 + c] = s;
  else if (c < 1536)  blat[l * 1536 + (c - 1024)] = s * 0.125f;
  else                blat[l * 1536 + 512 + (c - 1536)] = s;
}

__global__ __launch_bounds__(256) void k_fold_out(const float* __restrict__ Wout,
    ushort* __restrict__ woutT) {
  __shared__ float tile[32][33];
  int l = blockIdx.z;
  const float* Wl = Wout + (size_t)l * 524288;
  int r0 = blockIdx.y * 32, c0 = blockIdx.x * 32;
  int tx = threadIdx.x & 31, ty = threadIdx.x >> 5;
#pragma unroll
  for (int i = 0; i < 4; ++i)
    tile[ty + i * 8][tx] = Wl[(size_t)(r0 + ty + i * 8) * 1024 + c0 + tx];
  __syncthreads();
#pragma unroll
  for (int i = 0; i < 4; ++i) {
    int jl = ty + i * 8;
    woutT[(size_t)l * 524288 + (size_t)(c0 + jl) * 512 + r0 + tx] = f2bf(tile[tx][jl]);
  }
}

// ---------------------------------------------------------------------------
__global__ __launch_bounds__(256) void k_rownorm(const float* __restrict__ in,
    const float* __restrict__ pos, ushort* __restrict__ out) {
  int row = blockIdx.x, t = threadIdx.x;
  float4 v = *(const float4*)(in + (size_t)row * 1024 + t * 4);
  if (pos) {
    float4 p = *(const float4*)(pos + (size_t)(row & 511) * 1024 + t * 4);
    v.x += p.x; v.y += p.y; v.z += p.z; v.w += p.w;
  }
  float s = v.x + v.y + v.z + v.w;
  float q = v.x * v.x + v.y * v.y + v.z * v.z + v.w * v.w;
#pragma unroll
  for (int off = 32; off; off >>= 1) { s += __shfl_xor(s, off); q += __shfl_xor(q, off); }
  __shared__ float rs[4], rq[4];
  if ((t & 63) == 0) { rs[t >> 6] = s; rq[t >> 6] = q; }
  __syncthreads();
  s = rs[0] + rs[1] + rs[2] + rs[3];
  q = rq[0] + rq[1] + rq[2] + rq[3];
  float mean = s * (1.0f / 1024.0f);
  float var = q * (1.0f / 1024.0f) - mean * mean;
  float rstd = rsqrtf(var + 1e-5f);
  ushort4 o;
  o.x = f2bf((v.x - mean) * rstd);
  o.y = f2bf((v.y - mean) * rstd);
  o.z = f2bf((v.z - mean) * rstd);
  o.w = f2bf((v.w - mean) * rstd);
  *(ushort4*)(out + (size_t)row * 1024 + t * 4) = o;
}

__global__ __launch_bounds__(256) void k_finalln(const float* __restrict__ in,
    const float* __restrict__ g, const float* __restrict__ b, float* __restrict__ out) {
  int row = blockIdx.x, t = threadIdx.x;
  float4 v = *(const float4*)(in + (size_t)row * 1024 + t * 4);
  float s = v.x + v.y + v.z + v.w;
  float q = v.x * v.x + v.y * v.y + v.z * v.z + v.w * v.w;
#pragma unroll
  for (int off = 32; off; off >>= 1) { s += __shfl_xor(s, off); q += __shfl_xor(q, off); }
  __shared__ float rs[4], rq[4];
  if ((t & 63) == 0) { rs[t >> 6] = s; rq[t >> 6] = q; }
  __syncthreads();
  s = rs[0] + rs[1] + rs[2] + rs[3];
  q = rq[0] + rq[1] + rq[2] + rq[3];
  float mean = s * (1.0f / 1024.0f);
  float var = q * (1.0f / 1024.0f) - mean * mean;
  float rstd = rsqrtf(var + 1e-5f);
  float4 g4 = *(const float4*)(g + t * 4);
  float4 b4 = *(const float4*)(b + t * 4);
  float4 o;
  o.x = (v.x - mean) * rstd * g4.x + b4.x;
  o.y = (v.y - mean) * rstd * g4.y + b4.y;
  o.z = (v.z - mean) * rstd * g4.z + b4.z;
  o.w = (v.w - mean) * rstd * g4.w + b4.w;
  *(float4*)(out + (size_t)row * 1024 + t * 4) = o;
}

__global__ __launch_bounds__(256) void k_latinit(const float* __restrict__ latents,
                                                 float* __restrict__ lat) {
  int row = blockIdx.x, t = threadIdx.x;
  *(float4*)(lat + (size_t)row * 1024 + t * 4) =
      *(const float4*)(latents + (size_t)(row & 63) * 1024 + t * 4);
}

// ---------------------------------------------------------------------------
// 2-phase dbuf 64^2 GEMM (round-7 proven). MODE 3: latent merged
// (q | K_lat | V_lat->Vt). MODE 2: f32 residual += (out-proj).
template <int MODE>
__global__ __launch_bounds__(256) void k_gemm64(const ushort* __restrict__ A,
    const ushort* __restrict__ Bt, const float* __restrict__ bias,
    ushort* __restrict__ o0, ushort* __restrict__ o1, ushort* __restrict__ o2,
    float* __restrict__ of, int N, int K) {
  __shared__ ushort Al[2][64][32];
  __shared__ ushort Bl[2][64][32];
  __shared__ ushort Cl[64][72];
  int tid = threadIdx.x, lane = tid & 63, w = tid >> 6;
  int wr = w >> 1, wc = w & 1;
  int m0 = blockIdx.y * 64, n0 = blockIdx.x * 64;
  f32x4 acc[2][2] = {};
  const ushort* Ag = A + (size_t)(m0 + w * 16 + (lane >> 2)) * K + (lane & 3) * 8;
  const ushort* Bg = Bt + (size_t)(n0 + w * 16 + (lane >> 2)) * K + (lane & 3) * 8;
  int fr = lane & 15, fk = (lane >> 4) << 3;
  int nt = K >> 5;
  gld16(&Al[0][w * 16][0], Ag);
  gld16(&Bl[0][w * 16][0], Bg);
  __syncthreads();
  for (int t = 0; t < nt; ++t) {
    int cur = t & 1;
    if (t + 1 < nt) {
      int k0 = (t + 1) << 5;
      gld16(&Al[cur ^ 1][w * 16][0], Ag + k0);
      gld16(&Bl[cur ^ 1][w * 16][0], Bg + k0);
    }
    short8_t a[2], b[2];
#pragma unroll
    for (int mt = 0; mt < 2; ++mt)
      a[mt] = *(const short8_t*)&Al[cur][wr * 32 + mt * 16 + fr][fk];
#pragma unroll
    for (int nt2 = 0; nt2 < 2; ++nt2)
      b[nt2] = *(const short8_t*)&Bl[cur][wc * 32 + nt2 * 16 + fr][fk];
#pragma unroll
    for (int mt = 0; mt < 2; ++mt)
#pragma unroll
      for (int nt2 = 0; nt2 < 2; ++nt2)
        acc[mt][nt2] = mfma16(a[mt], b[nt2], acc[mt][nt2]);
    __syncthreads();
  }
  if constexpr (MODE == 3) {
    if (n0 >= 1024) {
#pragma unroll
      for (int mt = 0; mt < 2; ++mt)
#pragma unroll
        for (int nt2 = 0; nt2 < 2; ++nt2)
#pragma unroll
          for (int r = 0; r < 4; ++r) {
            int rl = wr * 32 + mt * 16 + ((lane >> 4) << 2) + r;
            int col = wc * 32 + nt2 * 16 + (lane & 15);
            Cl[rl][col] = f2bf(acc[mt][nt2][r] + bias[n0 + col]);
          }
      __syncthreads();
      int b_ = m0 >> 6;
#pragma unroll
      for (int q = 0; q < 2; ++q) {
        int task = tid + q * 256;
        int jg = task & 7, d = task >> 3;
        short8_t vv;
#pragma unroll
        for (int e = 0; e < 8; ++e) vv[e] = (short)Cl[jg * 8 + e][d];
        *(short8_t*)&o2[((size_t)(b_ * 512 + (n0 - 1024) + d)) * 576 + jg * 8] = vv;
      }
      return;
    }
  }
#pragma unroll
  for (int mt = 0; mt < 2; ++mt)
#pragma unroll
    for (int nt2 = 0; nt2 < 2; ++nt2)
#pragma unroll
      for (int r = 0; r < 4; ++r) {
        int row = m0 + wr * 32 + mt * 16 + ((lane >> 4) << 2) + r;
        int col = n0 + wc * 32 + nt2 * 16 + (lane & 15);
        float v = acc[mt][nt2][r] + (bias ? bias[col] : 0.0f);
        if constexpr (MODE == 3) {
          int b_ = row >> 6, ii = row & 63;
          if (col < 512) o0[(size_t)row * 512 + col] = f2bf(v);
          else           o1[(((size_t)(b_ * 576 + ii)) << 9) + (col - 512)] = f2bf(v);
        } else {
          of[(size_t)row * N + col] += v;
        }
      }
}

// ---------------------------------------------------------------------------
extern "C" void kernel_launch(void* const* d_in, const int* in_sizes, int n_in,
                              void* d_out, int out_size, void* d_ws, size_t ws_size,
                              hipStream_t stream) {
  const float* x       = (const float*)d_in[0];
  const int*   amask   = (const int*)d_in[1];
  const float* latents = (const float*)d_in[2];
  const float* pos     = (const float*)d_in[3];
  const float* lnmg    = (const float*)d_in[4];
  const float* lnmb    = (const float*)d_in[5];
  const float* lnlg    = (const float*)d_in[6];
  const float* lnlb    = (const float*)d_in[7];
  const float* Wq      = (const float*)d_in[8];
  const float* Wkv     = (const float*)d_in[9];
  const float* Wout    = (const float*)d_in[10];
  const float* fg      = (const float*)d_in[11];
  const float* fb      = (const float*)d_in[12];
  float* out = (float*)d_out;
  char* ws = (char*)d_ws;

  ushort* xhat  = (ushort*)(ws + 0);           // [16384][1024] bf16   32 MiB
  ushort* wkvmT = (ushort*)(ws + 33554432);    // [6][1024][1024]      12 MiB
  ushort* wlatT = (ushort*)(ws + 46137344);    // [6][1536][1024]      18 MiB
  ushort* woutT = (ushort*)(ws + 65011712);    // [6][1024][512]        6 MiB
  float*  bkvm  = (float*)(ws + 71303168);     // [6][1024]
  float*  blat  = (float*)(ws + 71327744);     // [6][1536]
  float*  lat   = (float*)(ws + 71364608);     // [2048][1024] f32      8 MiB
  ushort* lhat  = (ushort*)(ws + 79753216);    // [2048][1024] bf16     4 MiB
  ushort* qbuf  = (ushort*)(ws + 83947520);    // [2048][512]  bf16     2 MiB
  ushort* Kbuf  = (ushort*)(ws + 86044672);    // [32][576][512]       18 MiB
  ushort* Vt    = (ushort*)(ws + 104919040);   // [32][512][576]       18 MiB
  ushort* aobuf = (ushort*)(ws + 123793408);   // [2048][512]           2 MiB
  float*  pb    = (float*)(ws + 125890560);    // [6][32][2560] f32     2 MiB

  (void)hipFuncSetAttribute((const void*)k_gemm256m,
                            hipFuncAttributeMaxDynamicSharedMemorySize, 163840);
  (void)hipFuncSetAttribute((const void*)k_attn,
                            hipFuncAttributeMaxDynamicSharedMemorySize, 131072);

  dim3 B256(256);
  k_fold_kv<<<dim3(32, 32, 6), B256, 0, stream>>>(Wkv, lnmg, lnlg, lnmb, lnlb,
                                                  wkvmT, wlatT, pb);
  k_fold_q<<<dim3(16, 32, 6), B256, 0, stream>>>(Wq, lnlg, lnlb, wlatT, pb);
  k_fold_out<<<dim3(32, 16, 6), B256, 0, stream>>>(Wout, woutT);
  k_bias_red<<<dim3(10, 6), B256, 0, stream>>>(pb, bkvm, blat);
  k_rownorm<<<16384, B256, 0, stream>>>(x, pos, xhat);
  k_latinit<<<2048, B256, 0, stream>>>(latents, lat);

  for (int l = 0; l < 6; ++l) {
    k_rownorm<<<2048, B256, 0, stream>>>(lat, nullptr, lhat);
    // merged latent GEMM: [q | K_lat | V_lat], 64^2, 768 blocks
    k_gemm64<3><<<dim3(24, 32), B256, 0, stream>>>(
        lhat, wlatT + (size_t)l * 1572864, blat + l * 1536,
        qbuf, Kbuf, Vt, nullptr, 1536, 1024);
    // media KV: 256^2 pipelined
    k_gemm256m<<<dim3(256), dim3(512), 163840, stream>>>(
        xhat, wkvmT + (size_t)l * 1048576, bkvm + l * 1024, Kbuf, Vt);
    // attention: one block per (b,h)
    k_attn<<<dim3(256), dim3(512), 123904, stream>>>(qbuf, Kbuf, Vt, amask, aobuf);
    // lat += attn_out @ Wout, 64^2, 512 blocks
    k_gemm64<2><<<dim3(16, 32), B256, 0, stream>>>(
        aobuf, woutT + (size_t)l * 524288, nullptr,
        nullptr, nullptr, nullptr, lat, 1024, 512);
  }
  k_finalln<<<2048, B256, 0, stream>>>(lat, fg, fb, out);
}